// Round 24
// baseline (121.845 us; speedup 1.0000x reference)
//
#include <hip/hip_runtime.h>
#include <hip/hip_bf16.h>

typedef unsigned short u16;
typedef unsigned int u32;
typedef __attribute__((ext_vector_type(8))) short short8;
typedef __attribute__((ext_vector_type(8))) __bf16 bf16x8;
typedef __attribute__((ext_vector_type(4))) float f32x4;

#define DEV static __device__ __forceinline__

DEV float bf2f(u16 u) { unsigned v = ((unsigned)u) << 16; float f; __builtin_memcpy(&f, &v, 4); return f; }
DEV u16 f2bf(float f) {
  unsigned u; __builtin_memcpy(&u, &f, 4);
  unsigned lsb = (u >> 16) & 1;
  u += 0x7fffu + lsb;  // RNE
  return (u16)(u >> 16);
}
DEV float exp2fast(float x) { return __builtin_amdgcn_exp2f(x); }  // v_exp_f32
DEV f32x4 mfma16(short8 a, short8 b, f32x4 c) {
  return __builtin_amdgcn_mfma_f32_16x16x32_bf16(
      __builtin_bit_cast(bf16x8, a), __builtin_bit_cast(bf16x8, b), c, 0, 0, 0);
}
DEV short8 ld8(const u16* p) { return *(const short8*)p; }

// ---------------- fused weight prep + LN1 (blockIdx partition) ----------------
// Q cols (e<64) pre-scaled by log2e/8 so attention softmax needs no per-logit multiply.
__global__ __launch_bounds__(256) void prep_ln(const float* __restrict__ hw, const float* __restrict__ wo,
                                               const float* __restrict__ w1, const float* __restrict__ w2,
                                               u16* __restrict__ wqh, u16* __restrict__ wql,
                                               u16* __restrict__ woT, u16* __restrict__ w1T,
                                               u16* __restrict__ w2T,
                                               const float* __restrict__ zin, const float* __restrict__ lw,
                                               const float* __restrict__ lb,
                                               u16* __restrict__ hi, u16* __restrict__ lo) {
  if (blockIdx.x < 4608) {
    int idx = blockIdx.x * 256 + threadIdx.x;
    if (idx < 786432) {  // 8*512*192
      int e = idx % 192;
      int d = (idx / 192) % 512;
      int h = idx / (192 * 512);
      float v = hw[idx];
      if (e < 64) v *= 0.18033688011112043f;  // fold softmax scale (log2e/8) into Q
      int n = (e < 64) ? (h * 64 + e) : (e < 128) ? (512 + h * 64 + e - 64) : (1024 + h * 64 + e - 128);
      size_t oi = (size_t)n * 512 + d;
      u16 hh = f2bf(v);
      wqh[oi] = hh;
      if (e < 128) wql[oi] = f2bf(v - bf2f(hh));
    } else if (idx < 786432 + 262144) {
      int i = idx - 786432;  // wo: K=512, N=512
      int n = i % 512, k = i / 512;
      woT[(size_t)n * 512 + k] = f2bf(wo[i]);
    } else if (idx < 786432 + 262144 + 65536) {
      int i = idx - (786432 + 262144);  // w1: K=512, N=128
      int n = i % 128, k = i / 128;
      w1T[(size_t)n * 512 + k] = f2bf(w1[i]);
    } else if (idx < 786432 + 262144 + 131072) {
      int i = idx - (786432 + 262144 + 65536);  // w2: K=128, N=512
      int n = i % 512, k = i / 512;
      w2T[(size_t)n * 128 + k] = f2bf(w2[i]);
    }
    return;
  }
  // ---- LN1 path ----
  const int wv = threadIdx.x >> 6, lane = threadIdx.x & 63;
  const int row = (blockIdx.x - 4608) * 4 + wv;
  const float4* r = (const float4*)(zin + (size_t)row * 512);
  float4 a0 = r[lane * 2], a1 = r[lane * 2 + 1];
  float s = a0.x + a0.y + a0.z + a0.w + a1.x + a1.y + a1.z + a1.w;
  float ss = a0.x * a0.x + a0.y * a0.y + a0.z * a0.z + a0.w * a0.w +
             a1.x * a1.x + a1.y * a1.y + a1.z * a1.z + a1.w * a1.w;
#pragma unroll
  for (int m = 1; m < 64; m <<= 1) { s += __shfl_xor(s, m); ss += __shfl_xor(ss, m); }
  float mu = s * (1.f / 512.f);
  float var = ss * (1.f / 512.f) - mu * mu;
  float rstd = rsqrtf(var + 1e-5f);
  const float4* wp = (const float4*)lw + lane * 2;
  const float4* bp = (const float4*)lb + lane * 2;
  float4 w0 = wp[0], w1v = wp[1], b0 = bp[0], b1v = bp[1];
  float xv[8] = {a0.x, a0.y, a0.z, a0.w, a1.x, a1.y, a1.z, a1.w};
  float wv8[8] = {w0.x, w0.y, w0.z, w0.w, w1v.x, w1v.y, w1v.z, w1v.w};
  float bv8[8] = {b0.x, b0.y, b0.z, b0.w, b1v.x, b1v.y, b1v.z, b1v.w};
  short8 oh, ol;
#pragma unroll
  for (int i = 0; i < 8; i++) {
    float v = (xv[i] - mu) * rstd * wv8[i] + bv8[i];
    u16 hh = f2bf(v);
    oh[i] = (short)hh;
    ol[i] = (short)f2bf(v - bf2f(hh));
  }
  *(short8*)(hi + (size_t)row * 512 + lane * 8) = oh;
  *(short8*)(lo + (size_t)row * 512 + lane * 8) = ol;
}

// ---------------- LayerNorm: f32 (rows x 512) -> bf16 hi/lo ----------------
__global__ __launch_bounds__(256) void ln_kernel(const float* __restrict__ in,
                                                 const float* __restrict__ w,
                                                 const float* __restrict__ bb,
                                                 u16* __restrict__ hi, u16* __restrict__ lo) {
  const int wv = threadIdx.x >> 6, lane = threadIdx.x & 63;
  const int row = blockIdx.x * 4 + wv;
  const float4* r = (const float4*)(in + (size_t)row * 512);
  float4 a0 = r[lane * 2], a1 = r[lane * 2 + 1];
  float s = a0.x + a0.y + a0.z + a0.w + a1.x + a1.y + a1.z + a1.w;
  float ss = a0.x * a0.x + a0.y * a0.y + a0.z * a0.z + a0.w * a0.w +
             a1.x * a1.x + a1.y * a1.y + a1.z * a1.z + a1.w * a1.w;
#pragma unroll
  for (int m = 1; m < 64; m <<= 1) { s += __shfl_xor(s, m); ss += __shfl_xor(ss, m); }
  float mu = s * (1.f / 512.f);
  float var = ss * (1.f / 512.f) - mu * mu;
  float rstd = rsqrtf(var + 1e-5f);
  const float4* wp = (const float4*)w + lane * 2;
  const float4* bp = (const float4*)bb + lane * 2;
  float4 w0 = wp[0], w1v = wp[1], b0 = bp[0], b1v = bp[1];
  float xv[8] = {a0.x, a0.y, a0.z, a0.w, a1.x, a1.y, a1.z, a1.w};
  float wv8[8] = {w0.x, w0.y, w0.z, w0.w, w1v.x, w1v.y, w1v.z, w1v.w};
  float bv8[8] = {b0.x, b0.y, b0.z, b0.w, b1v.x, b1v.y, b1v.z, b1v.w};
  short8 oh, ol;
#pragma unroll
  for (int i = 0; i < 8; i++) {
    float v = (xv[i] - mu) * rstd * wv8[i] + bv8[i];
    u16 hh = f2bf(v);
    oh[i] = (short)hh;
    ol[i] = (short)f2bf(v - bf2f(hh));
  }
  *(short8*)(hi + (size_t)row * 512 + lane * 8) = oh;
  *(short8*)(lo + (size_t)row * 512 + lane * 8) = ol;
}

// ---------------- QKV GEMM (r4 structure): BM=128, BN=64, grid (32,24) ----------------
__global__ __launch_bounds__(256) void gemm_qkv(const u16* __restrict__ Ah, const u16* __restrict__ Alo,
                                                const u16* __restrict__ Bh, const u16* __restrict__ Blo,
                                                u16* __restrict__ qkh, u16* __restrict__ qkl,
                                                u16* __restrict__ vT) {
  __shared__ __align__(16) u16 As[128][40], Asl[128][40], Bs[64][40], Bsl[64][40];
  const int tid = threadIdx.x, lane = tid & 63, wv = tid >> 6;
  const int wm = wv >> 1, wn = wv & 1, g = lane >> 4, r16 = lane & 15;
  const int bm = blockIdx.x * 128, bn = blockIdx.y * 64;
  const bool split = blockIdx.y < 16;
  short8 sA[2], sAl[2], sB, sBl;
  auto ldtile = [&](int kt) {
#pragma unroll
    for (int c = 0; c < 2; c++) {
      int ch = c * 256 + tid;
      sA[c] = ld8(Ah + (size_t)(bm + (ch >> 2)) * 512 + kt + (ch & 3) * 8);
      if (split) sAl[c] = ld8(Alo + (size_t)(bm + (ch >> 2)) * 512 + kt + (ch & 3) * 8);
    }
    sB = ld8(Bh + (size_t)(bn + (tid >> 2)) * 512 + kt + (tid & 3) * 8);
    if (split) sBl = ld8(Blo + (size_t)(bn + (tid >> 2)) * 512 + kt + (tid & 3) * 8);
  };
  f32x4 acc[4][2] = {};
  ldtile(0);
  for (int kt = 0; kt < 512; kt += 32) {
    __syncthreads();
#pragma unroll
    for (int c = 0; c < 2; c++) {
      int ch = c * 256 + tid;
      *(short8*)&As[ch >> 2][(ch & 3) * 8] = sA[c];
      if (split) *(short8*)&Asl[ch >> 2][(ch & 3) * 8] = sAl[c];
    }
    *(short8*)&Bs[tid >> 2][(tid & 3) * 8] = sB;
    if (split) *(short8*)&Bsl[tid >> 2][(tid & 3) * 8] = sBl;
    __syncthreads();
    if (kt + 32 < 512) ldtile(kt + 32);
    short8 af[4], bf_[2], afl[4], bfl[2];
#pragma unroll
    for (int mi = 0; mi < 4; mi++) af[mi] = *(const short8*)&As[wm * 64 + mi * 16 + r16][g * 8];
#pragma unroll
    for (int ni = 0; ni < 2; ni++) bf_[ni] = *(const short8*)&Bs[wn * 32 + ni * 16 + r16][g * 8];
    if (split) {
#pragma unroll
      for (int mi = 0; mi < 4; mi++) afl[mi] = *(const short8*)&Asl[wm * 64 + mi * 16 + r16][g * 8];
#pragma unroll
      for (int ni = 0; ni < 2; ni++) bfl[ni] = *(const short8*)&Bsl[wn * 32 + ni * 16 + r16][g * 8];
    }
#pragma unroll
    for (int mi = 0; mi < 4; mi++)
#pragma unroll
      for (int ni = 0; ni < 2; ni++) {
        acc[mi][ni] = mfma16(af[mi], bf_[ni], acc[mi][ni]);
        if (split) {
          acc[mi][ni] = mfma16(af[mi], bfl[ni], acc[mi][ni]);
          acc[mi][ni] = mfma16(afl[mi], bf_[ni], acc[mi][ni]);
        }
      }
  }
#pragma unroll
  for (int mi = 0; mi < 4; mi++)
#pragma unroll
    for (int ni = 0; ni < 2; ni++) {
      int col = bn + wn * 32 + ni * 16 + r16;
      int row0 = bm + wm * 64 + mi * 16 + g * 4;
      if (split) {
#pragma unroll
        for (int j = 0; j < 4; j++) {
          size_t oi = (size_t)(row0 + j) * 1024 + col;
          float v = acc[mi][ni][j];
          u16 hh = f2bf(v);
          qkh[oi] = hh;
          qkl[oi] = f2bf(v - bf2f(hh));
        }
      } else {
        int vcol = col - 1024;
        ushort4 pk;
        pk.x = f2bf(acc[mi][ni][0]);
        pk.y = f2bf(acc[mi][ni][1]);
        pk.z = f2bf(acc[mi][ni][2]);
        pk.w = f2bf(acc[mi][ni][3]);
        *(ushort4*)(vT + (size_t)vcol * 4096 + row0) = pk;
      }
    }
}

// ---------------- generic GEMM (r13-exact, BK=32) ----------------
template <int MF, int NF, int EPI>
__global__ __launch_bounds__(256) void gemm_g(const u16* __restrict__ A, const u16* __restrict__ BT,
                                              const float* __restrict__ res, const float* __restrict__ bias,
                                              u16* __restrict__ outb, float* __restrict__ outf,
                                              int N, int K) {
  constexpr int BM = 32 * MF, BN = 32 * NF;
  constexpr int CA = (BM * 4 + 255) / 256, CB = (BN * 4 + 255) / 256;
  __shared__ __align__(16) u16 As[BM][40], Bs[BN][40];
  const int tid = threadIdx.x, lane = tid & 63, wv = tid >> 6;
  const int wm = wv >> 1, wn = wv & 1, g = lane >> 4, r16 = lane & 15;
  const int bm = blockIdx.x * BM, bn = blockIdx.y * BN;
  short8 sA[CA], sB[CB];
  auto ldtile = [&](int kt) {
#pragma unroll
    for (int c = 0; c < CA; c++) {
      int ch = c * 256 + tid;
      if (ch < BM * 4) sA[c] = ld8(A + (size_t)(bm + (ch >> 2)) * K + kt + (ch & 3) * 8);
    }
#pragma unroll
    for (int c = 0; c < CB; c++) {
      int ch = c * 256 + tid;
      if (ch < BN * 4) sB[c] = ld8(BT + (size_t)(bn + (ch >> 2)) * K + kt + (ch & 3) * 8);
    }
  };
  f32x4 acc[MF][NF] = {};
  ldtile(0);
  for (int kt = 0; kt < K; kt += 32) {
    __syncthreads();
#pragma unroll
    for (int c = 0; c < CA; c++) {
      int ch = c * 256 + tid;
      if (ch < BM * 4) *(short8*)&As[ch >> 2][(ch & 3) * 8] = sA[c];
    }
#pragma unroll
    for (int c = 0; c < CB; c++) {
      int ch = c * 256 + tid;
      if (ch < BN * 4) *(short8*)&Bs[ch >> 2][(ch & 3) * 8] = sB[c];
    }
    __syncthreads();
    if (kt + 32 < K) ldtile(kt + 32);
    short8 af[MF], bf_[NF];
#pragma unroll
    for (int mi = 0; mi < MF; mi++) af[mi] = *(const short8*)&As[wm * 16 * MF + mi * 16 + r16][g * 8];
#pragma unroll
    for (int ni = 0; ni < NF; ni++) bf_[ni] = *(const short8*)&Bs[wn * 16 * NF + ni * 16 + r16][g * 8];
#pragma unroll
    for (int mi = 0; mi < MF; mi++)
#pragma unroll
      for (int ni = 0; ni < NF; ni++) acc[mi][ni] = mfma16(af[mi], bf_[ni], acc[mi][ni]);
  }
#pragma unroll
  for (int mi = 0; mi < MF; mi++)
#pragma unroll
    for (int ni = 0; ni < NF; ni++) {
      int col = bn + wn * 16 * NF + ni * 16 + r16;
      int row0 = bm + wm * 16 * MF + mi * 16 + g * 4;
#pragma unroll
      for (int j = 0; j < 4; j++) {
        size_t oi = (size_t)(row0 + j) * N + col;
        float v = acc[mi][ni][j];
        if (EPI == 1) {
          outf[oi] = v + res[oi];
        } else if (EPI == 2) {
          outb[oi] = f2bf(v + bias[col]);
        } else {
          float u = v + bias[col];
          float gl = 0.5f * u * (1.0f + erff(u * 0.70710678118f));
          outf[oi] = gl + res[oi];
        }
      }
    }
}

// ---------------- flash attention (r23 + Q-scale fold + max3 reduce) ----------------
// Logits arrive pre-scaled to log2 domain (fold in prep); max reduce in nested-triple
// form so clang fuses to v_max3_f32. Hoisted lane-partial denominator (r23).
__global__ __launch_bounds__(256) void attn_kernel(const u16* __restrict__ qkh,
                                                   const u16* __restrict__ qkl,
                                                   const u16* __restrict__ vT,
                                                   u16* __restrict__ o) {
  constexpr int SK = 72, SV = 136, SP = 136;
  __shared__ __align__(16) u16 Kh[128 * SK], Kl[128 * SK], Vt[64 * SV];
  __shared__ __align__(16) u16 Pl[4][16 * SP];
  const int tid = threadIdx.x, lane = tid & 63, w = tid >> 6;
  const int g = lane >> 4, r16 = lane & 15;
  const int bid = blockIdx.x;
  const int swz = (bid & 7) * 64 + (bid >> 3);  // bijective: 512 = 8 * 64
  const int bh = swz >> 5;                      // 0..15: (b,h) panel
  const int qb = (swz & 31) * 64;               // q-block within panel
  const int b = bh >> 3, h = bh & 7;
  const size_t bbase = (size_t)b * 2048 * 1024;
  const u16* Qh = qkh + bbase + h * 64;
  const u16* Ql = qkl + bbase + h * 64;
  const u16* KgH = qkh + bbase + 512 + h * 64;
  const u16* KgL = qkl + bbase + 512 + h * 64;
  const u16* Vtg = vT + (size_t)h * 64 * 4096 + (size_t)b * 2048;  // [d][kv]

  const int qrow = qb + w * 16 + r16;
  short8 qh[2], qlo[2];
#pragma unroll
  for (int ks = 0; ks < 2; ks++) {
    qh[ks] = ld8(Qh + (size_t)qrow * 1024 + ks * 32 + g * 8);
    qlo[ks] = ld8(Ql + (size_t)qrow * 1024 + ks * 32 + g * 8);
  }

  f32x4 oacc[4] = {};
  float m_r = -3e38f, l_p = 0.f;  // m: row max (uniform across row's 4 g-lanes); l_p: lane-partial denom

  const int vd0 = tid >> 4, vkv = (tid & 15) * 8;
  short8 kA[4], kB[4], vS[4];
  auto ldkv = [&](int kt) {
#pragma unroll
    for (int c = 0; c < 4; c++) {
      int ch = c * 256 + tid;
      int kr = ch >> 3, kc = (ch & 7) * 8;
      kA[c] = ld8(KgH + (size_t)(kt + kr) * 1024 + kc);
      kB[c] = ld8(KgL + (size_t)(kt + kr) * 1024 + kc);
    }
#pragma unroll
    for (int c = 0; c < 4; c++)
      vS[c] = ld8(Vtg + (size_t)(vd0 + c * 16) * 4096 + kt + vkv);
  };
  ldkv(0);

  for (int kt = 0; kt < 2048; kt += 128) {
    __syncthreads();
#pragma unroll
    for (int c = 0; c < 4; c++) {
      int ch = c * 256 + tid;
      int kr = ch >> 3, kc = (ch & 7) * 8;
      *(short8*)&Kh[kr * SK + kc] = kA[c];
      *(short8*)&Kl[kr * SK + kc] = kB[c];
    }
#pragma unroll
    for (int c = 0; c < 4; c++)
      *(short8*)&Vt[(vd0 + c * 16) * SV + vkv] = vS[c];
    __syncthreads();
    if (kt + 128 < 2048) ldkv(kt + 128);
    // ---- QK^T SWAPPED (split: hi*hi + hi*lo + lo*hi): s[f] = K x Q (pre-scaled) ----
    __builtin_amdgcn_s_setprio(1);
    f32x4 s[8];
#pragma unroll
    for (int f = 0; f < 8; f++) {
      s[f] = f32x4{0.f, 0.f, 0.f, 0.f};
#pragma unroll
      for (int ks = 0; ks < 2; ks++) {
        short8 bh2 = *(const short8*)&Kh[(f * 16 + r16) * SK + ks * 32 + g * 8];
        short8 bl2 = *(const short8*)&Kl[(f * 16 + r16) * SK + ks * 32 + g * 8];
        s[f] = mfma16(bh2, qh[ks], s[f]);
        s[f] = mfma16(bl2, qh[ks], s[f]);
        s[f] = mfma16(bh2, qlo[ks], s[f]);
      }
    }
    __builtin_amdgcn_s_setprio(0);
    // ---- in-register online softmax; logits already log2-domain; max3-shaped reduce ----
    float mf[8];
#pragma unroll
    for (int f = 0; f < 8; f++)
      mf[f] = fmaxf(fmaxf(fmaxf(s[f][0], s[f][1]), s[f][2]), s[f][3]);  // max3 + fmax
    float vm = fmaxf(fmaxf(fmaxf(fmaxf(mf[0], mf[1]), mf[2]),
                           fmaxf(fmaxf(mf[3], mf[4]), mf[5])),
                     fmaxf(mf[6], mf[7]));
    vm = fmaxf(vm, __shfl_xor(vm, 16));
    vm = fmaxf(vm, __shfl_xor(vm, 32));  // vm uniform across row's 4 g-lanes
    const bool skip = __all(vm - m_r <= 8.f);  // wave-uniform
    float mn;
    if (skip) {
      mn = m_r;  // keep old max; P bounded by 2^8
    } else {
      mn = fmaxf(m_r, vm);
      float scl = exp2fast(m_r - mn);  // identical across the row's 4 g-lanes
      m_r = mn;
      l_p *= scl;
#pragma unroll
      for (int j = 0; j < 4; j++) {
        float sj = __shfl(scl, (g << 4) + (g << 2) + j);
#pragma unroll
        for (int dt = 0; dt < 4; dt++) oacc[dt][j] *= sj;
      }
    }
#pragma unroll
    for (int f = 0; f < 8; f++) {
      float e0 = exp2fast(s[f][0] - mn), e1 = exp2fast(s[f][1] - mn);
      float e2 = exp2fast(s[f][2] - mn), e3 = exp2fast(s[f][3] - mn);
      l_p += (e0 + e1) + (e2 + e3);
      u32 u0, u1, u2, u3;
      __builtin_memcpy(&u0, &e0, 4);
      __builtin_memcpy(&u1, &e1, 4);
      __builtin_memcpy(&u2, &e2, 4);
      __builtin_memcpy(&u3, &e3, 4);
      uint2 pk;
      pk.x = (u0 >> 16) | (u1 & 0xFFFF0000u);  // bf16 pair (kv+0, kv+1), truncation
      pk.y = (u2 >> 16) | (u3 & 0xFFFF0000u);  // (kv+2, kv+3)
      *(uint2*)&Pl[w][r16 * SP + f * 16 + g * 4] = pk;  // 8B store, kv-consecutive
    }
    // ---- P@V ----
    __builtin_amdgcn_s_setprio(1);
#pragma unroll
    for (int ks = 0; ks < 4; ks++) {
      short8 pa = *(const short8*)&Pl[w][r16 * SP + ks * 32 + g * 8];
#pragma unroll
      for (int dt = 0; dt < 4; dt++) {
        short8 vb = *(const short8*)&Vt[(dt * 16 + r16) * SV + ks * 32 + g * 8];
        oacc[dt] = mfma16(pa, vb, oacc[dt]);
      }
    }
    __builtin_amdgcn_s_setprio(0);
  }
  // epilogue: complete deferred denominator reduce, then normalize
  float l_r = l_p;
  l_r += __shfl_xor(l_r, 16);
  l_r += __shfl_xor(l_r, 32);
#pragma unroll
  for (int j = 0; j < 4; j++) {
    float lj = __shfl(l_r, (g << 4) + (g << 2) + j);
    float il = 1.f / lj;
    int row = b * 2048 + qb + w * 16 + g * 4 + j;
#pragma unroll
    for (int dt = 0; dt < 4; dt++) {
      int col = h * 64 + dt * 16 + r16;
      o[(size_t)row * 512 + col] = f2bf(oacc[dt][j] * il);
    }
  }
}

// ---------------- launcher ----------------
extern "C" void kernel_launch(void* const* d_in, const int* in_sizes, int n_in,
                              void* d_out, int out_size, void* d_ws, size_t ws_size,
                              hipStream_t stream) {
  const float* z = (const float*)d_in[0];
  const float* head_w = (const float*)d_in[1];
  const float* w_o = (const float*)d_in[2];
  const float* ln_w = (const float*)d_in[3];
  const float* ln_b = (const float*)d_in[4];
  const float* w1 = (const float*)d_in[5];
  const float* b1 = (const float*)d_in[6];
  const float* w2 = (const float*)d_in[7];
  const float* b2 = (const float*)d_in[8];
  float* out = (float*)d_out;

  size_t off = 0;
  auto alc = [&](size_t n) {
    void* p = (char*)d_ws + off;
    off += (n + 255) & ~(size_t)255;
    return p;
  };
  u16* x_hi = (u16*)alc((size_t)4096 * 512 * 2);
  u16* x_lo = (u16*)alc((size_t)4096 * 512 * 2);
  u16* wqh = (u16*)alc((size_t)1536 * 512 * 2);
  u16* wql = (u16*)alc((size_t)1536 * 512 * 2);
  u16* woT = (u16*)alc((size_t)512 * 512 * 2);
  u16* w1T = (u16*)alc((size_t)128 * 512 * 2);
  u16* w2T = (u16*)alc((size_t)512 * 128 * 2);
  u16* qkh = (u16*)alc((size_t)4096 * 1024 * 2);
  u16* qkl = (u16*)alc((size_t)4096 * 1024 * 2);
  u16* vT = (u16*)alc((size_t)512 * 4096 * 2);
  u16* ob = (u16*)alc((size_t)4096 * 512 * 2);
  float* z2 = (float*)alc((size_t)4096 * 512 * 4);
  u16* tb = (u16*)alc((size_t)4096 * 128 * 2);

  // fused weight prep + LN1 (5632 blocks)
  prep_ln<<<5632, 256, 0, stream>>>(head_w, w_o, w1, w2, wqh, wql, woT, w1T, w2T,
                                    z, ln_w, ln_b, x_hi, x_lo);

  // QKV projection (r4 tiling); V written transposed to vT
  gemm_qkv<<<dim3(32, 24), 256, 0, stream>>>(x_hi, x_lo, wqh, wql, qkh, qkl, vT);

  // flash attention (XCD-swizzled flat grid of 512)
  attn_kernel<<<512, 256, 0, stream>>>(qkh, qkl, vT, ob);

  // z2 = o @ w_o + z
  gemm_g<2, 2, 1><<<dim3(64, 8), 256, 0, stream>>>(ob, woT, z, nullptr, nullptr, z2, 512, 512);

  // LN2
  ln_kernel<<<1024, 256, 0, stream>>>(z2, ln_w, ln_b, x_hi, x_lo);

  // t = y @ w1 + b1  (32x32 tiles, 512 blocks = 2/CU)
  gemm_g<1, 1, 2><<<dim3(128, 4), 256, 0, stream>>>(x_hi, w1T, nullptr, b1, tb, nullptr, 128, 512);

  // out = gelu(t @ w2 + b2) + z2
  gemm_g<2, 2, 3><<<dim3(64, 8), 256, 0, stream>>>(tb, w2T, z2, b2, nullptr, out, 512, 128);
}

// Round 25
// 121.198 us; speedup vs baseline: 1.0053x; 1.0053x over previous
//
#include <hip/hip_runtime.h>
#include <hip/hip_bf16.h>

typedef unsigned short u16;
typedef unsigned int u32;
typedef __attribute__((ext_vector_type(8))) short short8;
typedef __attribute__((ext_vector_type(8))) __bf16 bf16x8;
typedef __attribute__((ext_vector_type(4))) float f32x4;

#define DEV static __device__ __forceinline__

DEV float bf2f(u16 u) { unsigned v = ((unsigned)u) << 16; float f; __builtin_memcpy(&f, &v, 4); return f; }
DEV u16 f2bf(float f) {
  unsigned u; __builtin_memcpy(&u, &f, 4);
  unsigned lsb = (u >> 16) & 1;
  u += 0x7fffu + lsb;  // RNE
  return (u16)(u >> 16);
}
DEV float exp2fast(float x) { return __builtin_amdgcn_exp2f(x); }  // v_exp_f32
DEV f32x4 mfma16(short8 a, short8 b, f32x4 c) {
  return __builtin_amdgcn_mfma_f32_16x16x32_bf16(
      __builtin_bit_cast(bf16x8, a), __builtin_bit_cast(bf16x8, b), c, 0, 0, 0);
}
DEV short8 ld8(const u16* p) { return *(const short8*)p; }

// ---------------- fused weight prep + LN1 (blockIdx partition) ----------------
__global__ __launch_bounds__(256) void prep_ln(const float* __restrict__ hw, const float* __restrict__ wo,
                                               const float* __restrict__ w1, const float* __restrict__ w2,
                                               u16* __restrict__ wqh, u16* __restrict__ wql,
                                               u16* __restrict__ woT, u16* __restrict__ w1T,
                                               u16* __restrict__ w2T,
                                               const float* __restrict__ zin, const float* __restrict__ lw,
                                               const float* __restrict__ lb,
                                               u16* __restrict__ hi, u16* __restrict__ lo) {
  if (blockIdx.x < 4608) {
    int idx = blockIdx.x * 256 + threadIdx.x;
    if (idx < 786432) {  // 8*512*192
      int e = idx % 192;
      int d = (idx / 192) % 512;
      int h = idx / (192 * 512);
      float v = hw[idx];
      int n = (e < 64) ? (h * 64 + e) : (e < 128) ? (512 + h * 64 + e - 64) : (1024 + h * 64 + e - 128);
      size_t oi = (size_t)n * 512 + d;
      u16 hh = f2bf(v);
      wqh[oi] = hh;
      if (e < 128) wql[oi] = f2bf(v - bf2f(hh));
    } else if (idx < 786432 + 262144) {
      int i = idx - 786432;  // wo: K=512, N=512
      int n = i % 512, k = i / 512;
      woT[(size_t)n * 512 + k] = f2bf(wo[i]);
    } else if (idx < 786432 + 262144 + 65536) {
      int i = idx - (786432 + 262144);  // w1: K=512, N=128
      int n = i % 128, k = i / 128;
      w1T[(size_t)n * 512 + k] = f2bf(w1[i]);
    } else if (idx < 786432 + 262144 + 131072) {
      int i = idx - (786432 + 262144 + 65536);  // w2: K=128, N=512
      int n = i % 512, k = i / 512;
      w2T[(size_t)n * 128 + k] = f2bf(w2[i]);
    }
    return;
  }
  // ---- LN1 path ----
  const int wv = threadIdx.x >> 6, lane = threadIdx.x & 63;
  const int row = (blockIdx.x - 4608) * 4 + wv;
  const float4* r = (const float4*)(zin + (size_t)row * 512);
  float4 a0 = r[lane * 2], a1 = r[lane * 2 + 1];
  float s = a0.x + a0.y + a0.z + a0.w + a1.x + a1.y + a1.z + a1.w;
  float ss = a0.x * a0.x + a0.y * a0.y + a0.z * a0.z + a0.w * a0.w +
             a1.x * a1.x + a1.y * a1.y + a1.z * a1.z + a1.w * a1.w;
#pragma unroll
  for (int m = 1; m < 64; m <<= 1) { s += __shfl_xor(s, m); ss += __shfl_xor(ss, m); }
  float mu = s * (1.f / 512.f);
  float var = ss * (1.f / 512.f) - mu * mu;
  float rstd = rsqrtf(var + 1e-5f);
  const float4* wp = (const float4*)lw + lane * 2;
  const float4* bp = (const float4*)lb + lane * 2;
  float4 w0 = wp[0], w1v = wp[1], b0 = bp[0], b1v = bp[1];
  float xv[8] = {a0.x, a0.y, a0.z, a0.w, a1.x, a1.y, a1.z, a1.w};
  float wv8[8] = {w0.x, w0.y, w0.z, w0.w, w1v.x, w1v.y, w1v.z, w1v.w};
  float bv8[8] = {b0.x, b0.y, b0.z, b0.w, b1v.x, b1v.y, b1v.z, b1v.w};
  short8 oh, ol;
#pragma unroll
  for (int i = 0; i < 8; i++) {
    float v = (xv[i] - mu) * rstd * wv8[i] + bv8[i];
    u16 hh = f2bf(v);
    oh[i] = (short)hh;
    ol[i] = (short)f2bf(v - bf2f(hh));
  }
  *(short8*)(hi + (size_t)row * 512 + lane * 8) = oh;
  *(short8*)(lo + (size_t)row * 512 + lane * 8) = ol;
}

// ---------------- LayerNorm: f32 (rows x 512) -> bf16 hi/lo ----------------
__global__ __launch_bounds__(256) void ln_kernel(const float* __restrict__ in,
                                                 const float* __restrict__ w,
                                                 const float* __restrict__ bb,
                                                 u16* __restrict__ hi, u16* __restrict__ lo) {
  const int wv = threadIdx.x >> 6, lane = threadIdx.x & 63;
  const int row = blockIdx.x * 4 + wv;
  const float4* r = (const float4*)(in + (size_t)row * 512);
  float4 a0 = r[lane * 2], a1 = r[lane * 2 + 1];
  float s = a0.x + a0.y + a0.z + a0.w + a1.x + a1.y + a1.z + a1.w;
  float ss = a0.x * a0.x + a0.y * a0.y + a0.z * a0.z + a0.w * a0.w +
             a1.x * a1.x + a1.y * a1.y + a1.z * a1.z + a1.w * a1.w;
#pragma unroll
  for (int m = 1; m < 64; m <<= 1) { s += __shfl_xor(s, m); ss += __shfl_xor(ss, m); }
  float mu = s * (1.f / 512.f);
  float var = ss * (1.f / 512.f) - mu * mu;
  float rstd = rsqrtf(var + 1e-5f);
  const float4* wp = (const float4*)w + lane * 2;
  const float4* bp = (const float4*)bb + lane * 2;
  float4 w0 = wp[0], w1v = wp[1], b0 = bp[0], b1v = bp[1];
  float xv[8] = {a0.x, a0.y, a0.z, a0.w, a1.x, a1.y, a1.z, a1.w};
  float wv8[8] = {w0.x, w0.y, w0.z, w0.w, w1v.x, w1v.y, w1v.z, w1v.w};
  float bv8[8] = {b0.x, b0.y, b0.z, b0.w, b1v.x, b1v.y, b1v.z, b1v.w};
  short8 oh, ol;
#pragma unroll
  for (int i = 0; i < 8; i++) {
    float v = (xv[i] - mu) * rstd * wv8[i] + bv8[i];
    u16 hh = f2bf(v);
    oh[i] = (short)hh;
    ol[i] = (short)f2bf(v - bf2f(hh));
  }
  *(short8*)(hi + (size_t)row * 512 + lane * 8) = oh;
  *(short8*)(lo + (size_t)row * 512 + lane * 8) = ol;
}

// ---------------- QKV GEMM (r4 structure): BM=128, BN=64, grid (32,24) ----------------
__global__ __launch_bounds__(256) void gemm_qkv(const u16* __restrict__ Ah, const u16* __restrict__ Alo,
                                                const u16* __restrict__ Bh, const u16* __restrict__ Blo,
                                                u16* __restrict__ qkh, u16* __restrict__ qkl,
                                                u16* __restrict__ vT) {
  __shared__ __align__(16) u16 As[128][40], Asl[128][40], Bs[64][40], Bsl[64][40];
  const int tid = threadIdx.x, lane = tid & 63, wv = tid >> 6;
  const int wm = wv >> 1, wn = wv & 1, g = lane >> 4, r16 = lane & 15;
  const int bm = blockIdx.x * 128, bn = blockIdx.y * 64;
  const bool split = blockIdx.y < 16;
  short8 sA[2], sAl[2], sB, sBl;
  auto ldtile = [&](int kt) {
#pragma unroll
    for (int c = 0; c < 2; c++) {
      int ch = c * 256 + tid;
      sA[c] = ld8(Ah + (size_t)(bm + (ch >> 2)) * 512 + kt + (ch & 3) * 8);
      if (split) sAl[c] = ld8(Alo + (size_t)(bm + (ch >> 2)) * 512 + kt + (ch & 3) * 8);
    }
    sB = ld8(Bh + (size_t)(bn + (tid >> 2)) * 512 + kt + (tid & 3) * 8);
    if (split) sBl = ld8(Blo + (size_t)(bn + (tid >> 2)) * 512 + kt + (tid & 3) * 8);
  };
  f32x4 acc[4][2] = {};
  ldtile(0);
  for (int kt = 0; kt < 512; kt += 32) {
    __syncthreads();
#pragma unroll
    for (int c = 0; c < 2; c++) {
      int ch = c * 256 + tid;
      *(short8*)&As[ch >> 2][(ch & 3) * 8] = sA[c];
      if (split) *(short8*)&Asl[ch >> 2][(ch & 3) * 8] = sAl[c];
    }
    *(short8*)&Bs[tid >> 2][(tid & 3) * 8] = sB;
    if (split) *(short8*)&Bsl[tid >> 2][(tid & 3) * 8] = sBl;
    __syncthreads();
    if (kt + 32 < 512) ldtile(kt + 32);
    short8 af[4], bf_[2], afl[4], bfl[2];
#pragma unroll
    for (int mi = 0; mi < 4; mi++) af[mi] = *(const short8*)&As[wm * 64 + mi * 16 + r16][g * 8];
#pragma unroll
    for (int ni = 0; ni < 2; ni++) bf_[ni] = *(const short8*)&Bs[wn * 32 + ni * 16 + r16][g * 8];
    if (split) {
#pragma unroll
      for (int mi = 0; mi < 4; mi++) afl[mi] = *(const short8*)&Asl[wm * 64 + mi * 16 + r16][g * 8];
#pragma unroll
      for (int ni = 0; ni < 2; ni++) bfl[ni] = *(const short8*)&Bsl[wn * 32 + ni * 16 + r16][g * 8];
    }
#pragma unroll
    for (int mi = 0; mi < 4; mi++)
#pragma unroll
      for (int ni = 0; ni < 2; ni++) {
        acc[mi][ni] = mfma16(af[mi], bf_[ni], acc[mi][ni]);
        if (split) {
          acc[mi][ni] = mfma16(af[mi], bfl[ni], acc[mi][ni]);
          acc[mi][ni] = mfma16(afl[mi], bf_[ni], acc[mi][ni]);
        }
      }
  }
#pragma unroll
  for (int mi = 0; mi < 4; mi++)
#pragma unroll
    for (int ni = 0; ni < 2; ni++) {
      int col = bn + wn * 32 + ni * 16 + r16;
      int row0 = bm + wm * 64 + mi * 16 + g * 4;
      if (split) {
#pragma unroll
        for (int j = 0; j < 4; j++) {
          size_t oi = (size_t)(row0 + j) * 1024 + col;
          float v = acc[mi][ni][j];
          u16 hh = f2bf(v);
          qkh[oi] = hh;
          qkl[oi] = f2bf(v - bf2f(hh));
        }
      } else {
        int vcol = col - 1024;
        ushort4 pk;
        pk.x = f2bf(acc[mi][ni][0]);
        pk.y = f2bf(acc[mi][ni][1]);
        pk.z = f2bf(acc[mi][ni][2]);
        pk.w = f2bf(acc[mi][ni][3]);
        *(ushort4*)(vT + (size_t)vcol * 4096 + row0) = pk;
      }
    }
}

// ---------------- generic GEMM (r13-exact, BK=32) ----------------
template <int MF, int NF, int EPI>
__global__ __launch_bounds__(256) void gemm_g(const u16* __restrict__ A, const u16* __restrict__ BT,
                                              const float* __restrict__ res, const float* __restrict__ bias,
                                              u16* __restrict__ outb, float* __restrict__ outf,
                                              int N, int K) {
  constexpr int BM = 32 * MF, BN = 32 * NF;
  constexpr int CA = (BM * 4 + 255) / 256, CB = (BN * 4 + 255) / 256;
  __shared__ __align__(16) u16 As[BM][40], Bs[BN][40];
  const int tid = threadIdx.x, lane = tid & 63, wv = tid >> 6;
  const int wm = wv >> 1, wn = wv & 1, g = lane >> 4, r16 = lane & 15;
  const int bm = blockIdx.x * BM, bn = blockIdx.y * BN;
  short8 sA[CA], sB[CB];
  auto ldtile = [&](int kt) {
#pragma unroll
    for (int c = 0; c < CA; c++) {
      int ch = c * 256 + tid;
      if (ch < BM * 4) sA[c] = ld8(A + (size_t)(bm + (ch >> 2)) * K + kt + (ch & 3) * 8);
    }
#pragma unroll
    for (int c = 0; c < CB; c++) {
      int ch = c * 256 + tid;
      if (ch < BN * 4) sB[c] = ld8(BT + (size_t)(bn + (ch >> 2)) * K + kt + (ch & 3) * 8);
    }
  };
  f32x4 acc[MF][NF] = {};
  ldtile(0);
  for (int kt = 0; kt < K; kt += 32) {
    __syncthreads();
#pragma unroll
    for (int c = 0; c < CA; c++) {
      int ch = c * 256 + tid;
      if (ch < BM * 4) *(short8*)&As[ch >> 2][(ch & 3) * 8] = sA[c];
    }
#pragma unroll
    for (int c = 0; c < CB; c++) {
      int ch = c * 256 + tid;
      if (ch < BN * 4) *(short8*)&Bs[ch >> 2][(ch & 3) * 8] = sB[c];
    }
    __syncthreads();
    if (kt + 32 < K) ldtile(kt + 32);
    short8 af[MF], bf_[NF];
#pragma unroll
    for (int mi = 0; mi < MF; mi++) af[mi] = *(const short8*)&As[wm * 16 * MF + mi * 16 + r16][g * 8];
#pragma unroll
    for (int ni = 0; ni < NF; ni++) bf_[ni] = *(const short8*)&Bs[wn * 16 * NF + ni * 16 + r16][g * 8];
#pragma unroll
    for (int mi = 0; mi < MF; mi++)
#pragma unroll
      for (int ni = 0; ni < NF; ni++) acc[mi][ni] = mfma16(af[mi], bf_[ni], acc[mi][ni]);
  }
#pragma unroll
  for (int mi = 0; mi < MF; mi++)
#pragma unroll
    for (int ni = 0; ni < NF; ni++) {
      int col = bn + wn * 16 * NF + ni * 16 + r16;
      int row0 = bm + wm * 16 * MF + mi * 16 + g * 4;
#pragma unroll
      for (int j = 0; j < 4; j++) {
        size_t oi = (size_t)(row0 + j) * N + col;
        float v = acc[mi][ni][j];
        if (EPI == 1) {
          outf[oi] = v + res[oi];
        } else if (EPI == 2) {
          outb[oi] = f2bf(v + bias[col]);
        } else {
          float u = v + bias[col];
          float gl = 0.5f * u * (1.0f + erff(u * 0.70710678118f));
          outf[oi] = gl + res[oi];
        }
      }
    }
}

// ---------------- flash attention (r23 final: swizzle + setprio + defer-max + hoisted denom) ----------------
__global__ __launch_bounds__(256) void attn_kernel(const u16* __restrict__ qkh,
                                                   const u16* __restrict__ qkl,
                                                   const u16* __restrict__ vT,
                                                   u16* __restrict__ o) {
  constexpr int SK = 72, SV = 136, SP = 136;
  __shared__ __align__(16) u16 Kh[128 * SK], Kl[128 * SK], Vt[64 * SV];
  __shared__ __align__(16) u16 Pl[4][16 * SP];
  const int tid = threadIdx.x, lane = tid & 63, w = tid >> 6;
  const int g = lane >> 4, r16 = lane & 15;
  const int bid = blockIdx.x;
  const int swz = (bid & 7) * 64 + (bid >> 3);  // bijective: 512 = 8 * 64
  const int bh = swz >> 5;                      // 0..15: (b,h) panel
  const int qb = (swz & 31) * 64;               // q-block within panel
  const int b = bh >> 3, h = bh & 7;
  const size_t bbase = (size_t)b * 2048 * 1024;
  const u16* Qh = qkh + bbase + h * 64;
  const u16* Ql = qkl + bbase + h * 64;
  const u16* KgH = qkh + bbase + 512 + h * 64;
  const u16* KgL = qkl + bbase + 512 + h * 64;
  const u16* Vtg = vT + (size_t)h * 64 * 4096 + (size_t)b * 2048;  // [d][kv]

  const int qrow = qb + w * 16 + r16;
  short8 qh[2], qlo[2];
#pragma unroll
  for (int ks = 0; ks < 2; ks++) {
    qh[ks] = ld8(Qh + (size_t)qrow * 1024 + ks * 32 + g * 8);
    qlo[ks] = ld8(Ql + (size_t)qrow * 1024 + ks * 32 + g * 8);
  }

  f32x4 oacc[4] = {};
  float m_r = -3e38f, l_p = 0.f;  // m: row max (uniform across the row's 4 g-lanes); l_p: LANE-partial denom

  const int vd0 = tid >> 4, vkv = (tid & 15) * 8;
  short8 kA[4], kB[4], vS[4];
  auto ldkv = [&](int kt) {
#pragma unroll
    for (int c = 0; c < 4; c++) {
      int ch = c * 256 + tid;
      int kr = ch >> 3, kc = (ch & 7) * 8;
      kA[c] = ld8(KgH + (size_t)(kt + kr) * 1024 + kc);
      kB[c] = ld8(KgL + (size_t)(kt + kr) * 1024 + kc);
    }
#pragma unroll
    for (int c = 0; c < 4; c++)
      vS[c] = ld8(Vtg + (size_t)(vd0 + c * 16) * 4096 + kt + vkv);
  };
  ldkv(0);

  for (int kt = 0; kt < 2048; kt += 128) {
    __syncthreads();
#pragma unroll
    for (int c = 0; c < 4; c++) {
      int ch = c * 256 + tid;
      int kr = ch >> 3, kc = (ch & 7) * 8;
      *(short8*)&Kh[kr * SK + kc] = kA[c];
      *(short8*)&Kl[kr * SK + kc] = kB[c];
    }
#pragma unroll
    for (int c = 0; c < 4; c++)
      *(short8*)&Vt[(vd0 + c * 16) * SV + vkv] = vS[c];
    __syncthreads();
    if (kt + 128 < 2048) ldkv(kt + 128);
    // ---- QK^T SWAPPED (split: hi*hi + hi*lo + lo*hi): s[f] = K x Q ----
    __builtin_amdgcn_s_setprio(1);
    f32x4 s[8];
#pragma unroll
    for (int f = 0; f < 8; f++) {
      s[f] = f32x4{0.f, 0.f, 0.f, 0.f};
#pragma unroll
      for (int ks = 0; ks < 2; ks++) {
        short8 bh2 = *(const short8*)&Kh[(f * 16 + r16) * SK + ks * 32 + g * 8];
        short8 bl2 = *(const short8*)&Kl[(f * 16 + r16) * SK + ks * 32 + g * 8];
        s[f] = mfma16(bh2, qh[ks], s[f]);
        s[f] = mfma16(bl2, qh[ks], s[f]);
        s[f] = mfma16(bh2, qlo[ks], s[f]);
      }
    }
    __builtin_amdgcn_s_setprio(0);
    // ---- in-register online softmax; T13 defer-max; lane-partial denominator ----
    constexpr float SCL2 = 0.125f * 1.44269504f;
    float a[8][4];
    float vm = -3e38f;
#pragma unroll
    for (int f = 0; f < 8; f++)
#pragma unroll
      for (int r = 0; r < 4; r++) {
        a[f][r] = s[f][r] * SCL2;
        vm = fmaxf(vm, a[f][r]);
      }
    vm = fmaxf(vm, __shfl_xor(vm, 16));
    vm = fmaxf(vm, __shfl_xor(vm, 32));  // vm now uniform across the row's 4 g-lanes
    const bool skip = __all(vm - m_r <= 8.f);  // wave-uniform
    float mn;
    if (skip) {
      mn = m_r;  // keep old max; P bounded by 2^8
    } else {
      mn = fmaxf(m_r, vm);
      float scl = exp2fast(m_r - mn);  // identical across the row's 4 g-lanes
      m_r = mn;
      l_p *= scl;
#pragma unroll
      for (int j = 0; j < 4; j++) {
        float sj = __shfl(scl, (g << 4) + (g << 2) + j);
#pragma unroll
        for (int dt = 0; dt < 4; dt++) oacc[dt][j] *= sj;
      }
    }
#pragma unroll
    for (int f = 0; f < 8; f++) {
      float e0 = exp2fast(a[f][0] - mn), e1 = exp2fast(a[f][1] - mn);
      float e2 = exp2fast(a[f][2] - mn), e3 = exp2fast(a[f][3] - mn);
      l_p += (e0 + e1) + (e2 + e3);
      u32 u0, u1, u2, u3;
      __builtin_memcpy(&u0, &e0, 4);
      __builtin_memcpy(&u1, &e1, 4);
      __builtin_memcpy(&u2, &e2, 4);
      __builtin_memcpy(&u3, &e3, 4);
      uint2 pk;
      pk.x = (u0 >> 16) | (u1 & 0xFFFF0000u);  // bf16 pair (kv+0, kv+1), truncation
      pk.y = (u2 >> 16) | (u3 & 0xFFFF0000u);  // (kv+2, kv+3)
      *(uint2*)&Pl[w][r16 * SP + f * 16 + g * 4] = pk;  // 8B store, kv-consecutive
    }
    // ---- P@V ----
    __builtin_amdgcn_s_setprio(1);
#pragma unroll
    for (int ks = 0; ks < 4; ks++) {
      short8 pa = *(const short8*)&Pl[w][r16 * SP + ks * 32 + g * 8];
#pragma unroll
      for (int dt = 0; dt < 4; dt++) {
        short8 vb = *(const short8*)&Vt[(dt * 16 + r16) * SV + ks * 32 + g * 8];
        oacc[dt] = mfma16(pa, vb, oacc[dt]);
      }
    }
    __builtin_amdgcn_s_setprio(0);
  }
  // epilogue: complete the deferred denominator reduce (row sum over 4 g-lanes), then normalize
  float l_r = l_p;
  l_r += __shfl_xor(l_r, 16);
  l_r += __shfl_xor(l_r, 32);
#pragma unroll
  for (int j = 0; j < 4; j++) {
    float lj = __shfl(l_r, (g << 4) + (g << 2) + j);
    float il = 1.f / lj;
    int row = b * 2048 + qb + w * 16 + g * 4 + j;
#pragma unroll
    for (int dt = 0; dt < 4; dt++) {
      int col = h * 64 + dt * 16 + r16;
      o[(size_t)row * 512 + col] = f2bf(oacc[dt][j] * il);
    }
  }
}

// ---------------- launcher ----------------
extern "C" void kernel_launch(void* const* d_in, const int* in_sizes, int n_in,
                              void* d_out, int out_size, void* d_ws, size_t ws_size,
                              hipStream_t stream) {
  const float* z = (const float*)d_in[0];
  const float* head_w = (const float*)d_in[1];
  const float* w_o = (const float*)d_in[2];
  const float* ln_w = (const float*)d_in[3];
  const float* ln_b = (const float*)d_in[4];
  const float* w1 = (const float*)d_in[5];
  const float* b1 = (const float*)d_in[6];
  const float* w2 = (const float*)d_in[7];
  const float* b2 = (const float*)d_in[8];
  float* out = (float*)d_out;

  size_t off = 0;
  auto alc = [&](size_t n) {
    void* p = (char*)d_ws + off;
    off += (n + 255) & ~(size_t)255;
    return p;
  };
  u16* x_hi = (u16*)alc((size_t)4096 * 512 * 2);
  u16* x_lo = (u16*)alc((size_t)4096 * 512 * 2);
  u16* wqh = (u16*)alc((size_t)1536 * 512 * 2);
  u16* wql = (u16*)alc((size_t)1536 * 512 * 2);
  u16* woT = (u16*)alc((size_t)512 * 512 * 2);
  u16* w1T = (u16*)alc((size_t)128 * 512 * 2);
  u16* w2T = (u16*)alc((size_t)512 * 128 * 2);
  u16* qkh = (u16*)alc((size_t)4096 * 1024 * 2);
  u16* qkl = (u16*)alc((size_t)4096 * 1024 * 2);
  u16* vT = (u16*)alc((size_t)512 * 4096 * 2);
  u16* ob = (u16*)alc((size_t)4096 * 512 * 2);
  float* z2 = (float*)alc((size_t)4096 * 512 * 4);
  u16* tb = (u16*)alc((size_t)4096 * 128 * 2);

  // fused weight prep + LN1 (5632 blocks)
  prep_ln<<<5632, 256, 0, stream>>>(head_w, w_o, w1, w2, wqh, wql, woT, w1T, w2T,
                                    z, ln_w, ln_b, x_hi, x_lo);

  // QKV projection (r4 tiling); V written transposed to vT
  gemm_qkv<<<dim3(32, 24), 256, 0, stream>>>(x_hi, x_lo, wqh, wql, qkh, qkl, vT);

  // flash attention (XCD-swizzled flat grid of 512)
  attn_kernel<<<512, 256, 0, stream>>>(qkh, qkl, vT, ob);

  // z2 = o @ w_o + z
  gemm_g<2, 2, 1><<<dim3(64, 8), 256, 0, stream>>>(ob, woT, z, nullptr, nullptr, z2, 512, 512);

  // LN2
  ln_kernel<<<1024, 256, 0, stream>>>(z2, ln_w, ln_b, x_hi, x_lo);

  // t = y @ w1 + b1  (32x32 tiles, 512 blocks = 2/CU)
  gemm_g<1, 1, 2><<<dim3(128, 4), 256, 0, stream>>>(x_hi, w1T, nullptr, b1, tb, nullptr, 128, 512);

  // out = gelu(t @ w2 + b2) + z2
  gemm_g<2, 2, 3><<<dim3(64, 8), 256, 0, stream>>>(tb, w2T, z2, b2, nullptr, out, 512, 128);
}